// Round 1
// baseline (6915.775 us; speedup 1.0000x reference)
//
#include <hip/hip_runtime.h>
#include <math.h>

#define NL 8
#define NP 512
#define NC 64
#define NF 128
#define NALL 192
#define NRAY (NL * NP)
#define HID 128

// d_coarse bins, exactly as reference: t = i/64, d = near*(1-t)+far*t
__device__ __forceinline__ float dcoarse_at(int i) {
    float t = (float)i * 0.015625f; // i/64, exact in fp32
    return 1e-3f * (1.0f - t) + 0.5f * t;
}

// SDF MLP 3->128->128->128->1, register-minimal formulation:
// phase 1: h2[j] = b1[j] + sum_k relu(x.W0[:,k]+b0[k]) * W1[k,j]   (h1 on the fly)
// phase 2: out = b3 + sum_j relu(b2[j] + sum_k relu(h2)[k]*W2[k,j]) * W3[j] (h3 on the fly)
__device__ float mlp_sdf(float x0, float x1, float x2,
                         const float* __restrict__ w0, const float* __restrict__ b0,
                         const float* __restrict__ w1, const float* __restrict__ b1,
                         const float* __restrict__ w2, const float* __restrict__ b2,
                         const float* __restrict__ w3, const float* __restrict__ b3) {
    float h[HID];
#pragma unroll
    for (int j = 0; j < HID; ++j) h[j] = b1[j];
#pragma unroll 1
    for (int k = 0; k < HID; ++k) {
        float h1 = fmaf(x2, w0[2 * HID + k], fmaf(x1, w0[HID + k], fmaf(x0, w0[k], b0[k])));
        h1 = fmaxf(h1, 0.0f);
        const float* wr = w1 + k * HID;
#pragma unroll
        for (int j = 0; j < HID; ++j) h[j] = fmaf(h1, wr[j], h[j]);
    }
#pragma unroll
    for (int j = 0; j < HID; ++j) h[j] = fmaxf(h[j], 0.0f);

    float out = b3[0];
#pragma unroll 1
    for (int jb = 0; jb < HID; jb += 16) {
        float acc[16];
#pragma unroll
        for (int t = 0; t < 16; ++t) acc[t] = b2[jb + t];
#pragma unroll
        for (int k = 0; k < HID; ++k) {
            const float* wr = w2 + k * HID + jb;
            float hk = h[k];
#pragma unroll
            for (int t = 0; t < 16; ++t) acc[t] = fmaf(hk, wr[t], acc[t]);
        }
#pragma unroll
        for (int t = 0; t < 16; ++t) out = fmaf(fmaxf(acc[t], 0.0f), w3[jb + t], out);
    }
    return out;
}

// Kernel A: sdf at the 64 coarse points of every ray. 1 thread per point.
__global__ __launch_bounds__(256) void coarse_kernel(
    const float* __restrict__ pts, const float* __restrict__ lights,
    const float* __restrict__ w0, const float* __restrict__ b0,
    const float* __restrict__ w1, const float* __restrict__ b1,
    const float* __restrict__ w2, const float* __restrict__ b2,
    const float* __restrict__ w3, const float* __restrict__ b3,
    float* __restrict__ sdf_c) {
    int tid = blockIdx.x * blockDim.x + threadIdx.x; // NRAY*NC
    int ray = tid >> 6;
    int i = tid & 63;
    int l = ray >> 9;     // / NP
    int p = ray & (NP - 1);
    float px = pts[p * 3 + 0], py = pts[p * 3 + 1], pz = pts[p * 3 + 2];
    float dx = lights[l * 3 + 0] - px, dy = lights[l * 3 + 1] - py, dz = lights[l * 3 + 2] - pz;
    float n = sqrtf(dx * dx + dy * dy + dz * dz);
    dx /= n; dy /= n; dz /= n;
    float d = dcoarse_at(i);
    float x0 = px + d * dx, x1 = py + d * dy, x2 = pz + d * dz;
    sdf_c[tid] = mlp_sdf(x0, x1, x2, w0, b0, w1, b1, w2, b2, w3, b3);
}

// Kernel B: per-ray — sdf_to_w on coarse, sample_pdf (exact searchsorted-count
// semantics), then bitonic sort of coarse+fine (padded to 256 with +inf).
__global__ __launch_bounds__(256) void sample_kernel(
    const float* __restrict__ sdf_c, const float* __restrict__ u,
    float* __restrict__ d_all) {
    int ray = blockIdx.x;
    int tid = threadIdx.x;
    __shared__ float csig[NC];
    __shared__ float alpha[NC - 1];
    __shared__ float wbuf[NC - 1];
    __shared__ float cdf[NC];       // cdf[0]=0, cdf[i]=cumsum(pdf)[i-1]
    __shared__ float sortbuf[256];

    if (tid < NC) {
        float s = sdf_c[ray * NC + tid];
        csig[tid] = 1.0f / (1.0f + expf(-100.0f * s));
    }
    __syncthreads();
    if (tid < NC - 1) {
        float a = (csig[tid] - csig[tid + 1]) / (csig[tid] + 1e-10f);
        alpha[tid] = fmaxf(a, 0.0f);
    }
    __syncthreads();
    if (tid == 0) {
        float T = 1.0f, wsum = 0.0f;
        for (int i = 0; i < NC - 1; ++i) {
            float w = alpha[i] * T + 1e-5f;   // w_coarse + 1e-5
            wbuf[i] = w;
            wsum += w;
            T *= (1.0f - alpha[i] + 1e-10f);
        }
        float c = 0.0f;
        cdf[0] = 0.0f;
        for (int i = 0; i < NC - 1; ++i) {
            c += wbuf[i] / wsum;
            cdf[i + 1] = c;
        }
    }
    __syncthreads();
    if (tid < NF) {
        float uu = u[ray * NF + tid];
        int inds = 0;
        for (int j = 0; j < NC; ++j) inds += (uu >= cdf[j]) ? 1 : 0;
        int below = min(max(inds - 1, 0), NC - 1);
        int above = min(inds, NC - 1);
        float cb = cdf[below], ca = cdf[above];
        float bb = dcoarse_at(below), ba = dcoarse_at(above);
        float denom = ca - cb;
        if (denom < 1e-5f) denom = 1.0f;
        float t = (uu - cb) / denom;
        sortbuf[NC + tid] = bb + t * (ba - bb);
    }
    if (tid < NC) sortbuf[tid] = dcoarse_at(tid);
    if (tid >= NALL) sortbuf[tid] = INFINITY;
    __syncthreads();
    // bitonic sort 256 elements, 256 threads
    for (int k = 2; k <= 256; k <<= 1) {
        for (int j = k >> 1; j > 0; j >>= 1) {
            int ixj = tid ^ j;
            if (ixj > tid) {
                float a = sortbuf[tid], b = sortbuf[ixj];
                bool up = ((tid & k) == 0);
                if (up ? (a > b) : (a < b)) {
                    sortbuf[tid] = b;
                    sortbuf[ixj] = a;
                }
            }
            __syncthreads();
        }
    }
    if (tid < NALL) d_all[ray * NALL + tid] = sortbuf[tid];
}

// Kernel C: sdf at the 192 merged points of every ray. 1 thread per point.
__global__ __launch_bounds__(256) void fine_kernel(
    const float* __restrict__ pts, const float* __restrict__ lights,
    const float* __restrict__ d_all,
    const float* __restrict__ w0, const float* __restrict__ b0,
    const float* __restrict__ w1, const float* __restrict__ b1,
    const float* __restrict__ w2, const float* __restrict__ b2,
    const float* __restrict__ w3, const float* __restrict__ b3,
    float* __restrict__ sdf_a) {
    int tid = blockIdx.x * blockDim.x + threadIdx.x; // NRAY*NALL
    int ray = tid / NALL;
    int l = ray >> 9;
    int p = ray & (NP - 1);
    float px = pts[p * 3 + 0], py = pts[p * 3 + 1], pz = pts[p * 3 + 2];
    float dx = lights[l * 3 + 0] - px, dy = lights[l * 3 + 1] - py, dz = lights[l * 3 + 2] - pz;
    float n = sqrtf(dx * dx + dy * dy + dz * dz);
    dx /= n; dy /= n; dz /= n;
    float d = d_all[tid];
    float x0 = px + d * dx, x1 = py + d * dy, x2 = pz + d * dz;
    sdf_a[tid] = mlp_sdf(x0, x1, x2, w0, b0, w1, b1, w2, b2, w3, b3);
}

// Kernel D: per-ray sdf_to_w on merged set, occu sum, out = 1-occu.
__global__ __launch_bounds__(192) void finish_kernel(
    const float* __restrict__ sdf_a, float* __restrict__ out) {
    int ray = blockIdx.x;
    int tid = threadIdx.x;
    __shared__ float csig[NALL];
    if (tid < NALL) {
        float s = sdf_a[ray * NALL + tid];
        csig[tid] = 1.0f / (1.0f + expf(-100.0f * s));
    }
    __syncthreads();
    if (tid == 0) {
        float T = 1.0f, occu = 0.0f;
        for (int i = 0; i < NALL - 1; ++i) {
            float a = fmaxf((csig[i] - csig[i + 1]) / (csig[i] + 1e-10f), 0.0f);
            occu += a * T;
            T *= (1.0f - a + 1e-10f);
        }
        out[ray] = 1.0f - occu;
    }
}

extern "C" void kernel_launch(void* const* d_in, const int* in_sizes, int n_in,
                              void* d_out, int out_size, void* d_ws, size_t ws_size,
                              hipStream_t stream) {
    const float* pts = (const float*)d_in[0];
    const float* lights = (const float*)d_in[1];
    const float* u = (const float*)d_in[2];
    const float* w0 = (const float*)d_in[3];
    const float* b0 = (const float*)d_in[4];
    const float* w1 = (const float*)d_in[5];
    const float* b1 = (const float*)d_in[6];
    const float* w2 = (const float*)d_in[7];
    const float* b2 = (const float*)d_in[8];
    const float* w3 = (const float*)d_in[9];
    const float* b3 = (const float*)d_in[10];
    float* out = (float*)d_out;

    // workspace layout (floats): [d_all: NRAY*NALL][sdf: NRAY*NALL]
    // sdf region is reused: coarse sdf (NRAY*NC) then fine sdf (NRAY*NALL).
    float* ws = (float*)d_ws;
    float* d_all = ws;
    float* sdf = ws + (size_t)NRAY * NALL;

    coarse_kernel<<<(NRAY * NC) / 256, 256, 0, stream>>>(
        pts, lights, w0, b0, w1, b1, w2, b2, w3, b3, sdf);
    sample_kernel<<<NRAY, 256, 0, stream>>>(sdf, u, d_all);
    fine_kernel<<<(NRAY * NALL) / 256, 256, 0, stream>>>(
        pts, lights, d_all, w0, b0, w1, b1, w2, b2, w3, b3, sdf);
    finish_kernel<<<NRAY, 192, 0, stream>>>(sdf, out);
}

// Round 2
// 851.123 us; speedup vs baseline: 8.1255x; 8.1255x over previous
//
#include <hip/hip_runtime.h>
#include <math.h>

#define NL 8
#define NP 512
#define NC 64
#define NF 128
#define NALL 192
#define NRAY (NL * NP)
#define HID 128
#define MT 128          // points per block
#define THREADS 256

__device__ __forceinline__ float dcoarse_at(int i) {
    float t = (float)i * 0.015625f; // i/64, exact in fp32
    return 1e-3f * (1.0f - t) + 0.5f * t;
}

// Fused 4-layer MLP over MT points per block.
// H[k][m] in LDS (64 KB). Weights streamed in K=32 panels into WB (16 KB).
// Thread tile 8m x 8j, swizzled so each wave covers an 8x8 (tm,tn) square:
// all k-loop LDS reads are <=2-way bank aliased (free per m136).
template<int MODE>   // 0: coarse (d computed), 1: fine (d from d_all)
__global__ __launch_bounds__(THREADS, 2) void mlp_kernel(
    const float* __restrict__ pts, const float* __restrict__ lights,
    const float* __restrict__ d_all,
    const float* __restrict__ w0, const float* __restrict__ b0,
    const float* __restrict__ w1, const float* __restrict__ b1,
    const float* __restrict__ w2, const float* __restrict__ b2,
    const float* __restrict__ w3, const float* __restrict__ b3,
    float* __restrict__ sdf_out)
{
    __shared__ float H[HID * MT];   // 64 KB: H[k*MT + m]
    __shared__ float WB[32 * HID];  // 16 KB: weight panel / coords+w0+b0 / partials

    const int tid = threadIdx.x;
    const int base = blockIdx.x * MT;

    // swizzled 16x16 thread grid: wave w covers tm,tn each spanning 8 values
    const int tm = (tid & 7) | ((tid >> 3) & 8);
    const int tn = ((tid >> 3) & 7) | ((tid >> 4) & 8);
    const int m0 = tm * 8;
    const int j0 = tn * 8;

    // ---- phase A: coords -> WB[0..384); w0 -> WB[384..768); b0 -> WB[768..896)
    if (tid < MT) {
        int pt = base + tid;
        int ray;
        float d;
        if (MODE == 0) { ray = pt >> 6; d = dcoarse_at(pt & 63); }
        else           { ray = pt / NALL; d = d_all[pt]; }
        int l = ray >> 9, p = ray & (NP - 1);
        float px = pts[p * 3 + 0], py = pts[p * 3 + 1], pz = pts[p * 3 + 2];
        float dx = lights[l * 3 + 0] - px, dy = lights[l * 3 + 1] - py, dz = lights[l * 3 + 2] - pz;
        float n = sqrtf(dx * dx + dy * dy + dz * dz);
        dx /= n; dy /= n; dz /= n;
        WB[0 * MT + tid] = px + d * dx;
        WB[1 * MT + tid] = py + d * dy;
        WB[2 * MT + tid] = pz + d * dz;
    } else {
        int t = tid - MT;  // 0..127, copy 384 floats of w0 + 128 of b0
        float4 v;
        if (t < 96) v = ((const float4*)w0)[t];
        else        v = ((const float4*)b0)[t - 96];
        ((float4*)(WB + 384))[t] = v;
    }
    __syncthreads();

    // ---- layer 1: H[j][m] = relu(b0[j] + sum_c X[c][m] * w0[c][j])
    {
        float acc[8][8];
        float bj[8];
#pragma unroll
        for (int ji = 0; ji < 8; ++ji) bj[ji] = WB[768 + j0 + ji];
#pragma unroll
        for (int mi = 0; mi < 8; ++mi)
#pragma unroll
            for (int ji = 0; ji < 8; ++ji) acc[mi][ji] = bj[ji];
#pragma unroll
        for (int c = 0; c < 3; ++c) {
            float a[8], b[8];
            *(float4*)&a[0] = *(const float4*)&WB[c * MT + m0];
            *(float4*)&a[4] = *(const float4*)&WB[c * MT + m0 + 4];
            *(float4*)&b[0] = *(const float4*)&WB[384 + c * HID + j0];
            *(float4*)&b[4] = *(const float4*)&WB[384 + c * HID + j0 + 4];
#pragma unroll
            for (int mi = 0; mi < 8; ++mi)
#pragma unroll
                for (int ji = 0; ji < 8; ++ji) acc[mi][ji] = fmaf(a[mi], b[ji], acc[mi][ji]);
        }
#pragma unroll
        for (int ji = 0; ji < 8; ++ji) {
            float4 v0 = make_float4(fmaxf(acc[0][ji], 0.f), fmaxf(acc[1][ji], 0.f),
                                    fmaxf(acc[2][ji], 0.f), fmaxf(acc[3][ji], 0.f));
            float4 v1 = make_float4(fmaxf(acc[4][ji], 0.f), fmaxf(acc[5][ji], 0.f),
                                    fmaxf(acc[6][ji], 0.f), fmaxf(acc[7][ji], 0.f));
            *(float4*)&H[(j0 + ji) * MT + m0] = v0;
            *(float4*)&H[(j0 + ji) * MT + m0 + 4] = v1;
        }
    }

    // ---- layers 2,3 (W1, W2); layer 2 writes back to H, layer 3 keeps acc in regs
    float acc[8][8];
#pragma unroll 1
    for (int layer = 0; layer < 2; ++layer) {
        const float* W = layer ? w2 : w1;
        const float* B = layer ? b2 : b1;
        {
            float bj[8];
#pragma unroll
            for (int ji = 0; ji < 8; ++ji) bj[ji] = B[j0 + ji];
#pragma unroll
            for (int mi = 0; mi < 8; ++mi)
#pragma unroll
                for (int ji = 0; ji < 8; ++ji) acc[mi][ji] = bj[ji];
        }
#pragma unroll 1
        for (int kp = 0; kp < 4; ++kp) {
            __syncthreads();   // prior WB reads done; (kp==0) H writes visible
            const float4* src = (const float4*)(W + kp * 32 * HID);
            float4* dst = (float4*)WB;
#pragma unroll
            for (int i = 0; i < 4; ++i) dst[tid + 256 * i] = src[tid + 256 * i];
            __syncthreads();
#pragma unroll 4
            for (int kk = 0; kk < 32; ++kk) {
                const int k = kp * 32 + kk;
                float a[8], b[8];
                *(float4*)&a[0] = *(const float4*)&H[k * MT + m0];
                *(float4*)&a[4] = *(const float4*)&H[k * MT + m0 + 4];
                *(float4*)&b[0] = *(const float4*)&WB[kk * HID + j0];
                *(float4*)&b[4] = *(const float4*)&WB[kk * HID + j0 + 4];
#pragma unroll
                for (int mi = 0; mi < 8; ++mi)
#pragma unroll
                    for (int ji = 0; ji < 8; ++ji) acc[mi][ji] = fmaf(a[mi], b[ji], acc[mi][ji]);
            }
        }
        if (layer == 0) {
            __syncthreads();   // all H reads done before overwrite
#pragma unroll
            for (int ji = 0; ji < 8; ++ji) {
                float4 v0 = make_float4(fmaxf(acc[0][ji], 0.f), fmaxf(acc[1][ji], 0.f),
                                        fmaxf(acc[2][ji], 0.f), fmaxf(acc[3][ji], 0.f));
                float4 v1 = make_float4(fmaxf(acc[4][ji], 0.f), fmaxf(acc[5][ji], 0.f),
                                        fmaxf(acc[6][ji], 0.f), fmaxf(acc[7][ji], 0.f));
                *(float4*)&H[(j0 + ji) * MT + m0] = v0;
                *(float4*)&H[(j0 + ji) * MT + m0 + 4] = v1;
            }
        }
    }

    // ---- layer 4: out[m] = b3 + sum_j relu(h3[j][m]) * w3[j], via partials in WB
    __syncthreads();           // all WB panel reads done
    {
        float w3r[8];
#pragma unroll
        for (int ji = 0; ji < 8; ++ji) w3r[ji] = w3[j0 + ji];
#pragma unroll
        for (int mi = 0; mi < 8; ++mi) {
            float p = 0.f;
#pragma unroll
            for (int ji = 0; ji < 8; ++ji) p = fmaf(fmaxf(acc[mi][ji], 0.f), w3r[ji], p);
            WB[tn * MT + m0 + mi] = p;
        }
    }
    __syncthreads();
    if (tid < MT) {
        float s = b3[0];
#pragma unroll
        for (int t = 0; t < 16; ++t) s += WB[t * MT + tid];
        sdf_out[base + tid] = s;
    }
}

// Per-ray: sdf_to_w on coarse, sample_pdf (exact searchsorted-count semantics),
// then bitonic sort of coarse+fine (padded to 256 with +inf).
__global__ __launch_bounds__(256) void sample_kernel(
    const float* __restrict__ sdf_c, const float* __restrict__ u,
    float* __restrict__ d_all) {
    int ray = blockIdx.x;
    int tid = threadIdx.x;
    __shared__ float csig[NC];
    __shared__ float alpha[NC - 1];
    __shared__ float wbuf[NC - 1];
    __shared__ float cdf[NC];
    __shared__ float sortbuf[256];

    if (tid < NC) {
        float s = sdf_c[ray * NC + tid];
        csig[tid] = 1.0f / (1.0f + expf(-100.0f * s));
    }
    __syncthreads();
    if (tid < NC - 1) {
        float a = (csig[tid] - csig[tid + 1]) / (csig[tid] + 1e-10f);
        alpha[tid] = fmaxf(a, 0.0f);
    }
    __syncthreads();
    if (tid == 0) {
        float T = 1.0f, wsum = 0.0f;
        for (int i = 0; i < NC - 1; ++i) {
            float w = alpha[i] * T + 1e-5f;
            wbuf[i] = w;
            wsum += w;
            T *= (1.0f - alpha[i] + 1e-10f);
        }
        float c = 0.0f;
        cdf[0] = 0.0f;
        for (int i = 0; i < NC - 1; ++i) {
            c += wbuf[i] / wsum;
            cdf[i + 1] = c;
        }
    }
    __syncthreads();
    if (tid < NF) {
        float uu = u[ray * NF + tid];
        int inds = 0;
        for (int j = 0; j < NC; ++j) inds += (uu >= cdf[j]) ? 1 : 0;
        int below = min(max(inds - 1, 0), NC - 1);
        int above = min(inds, NC - 1);
        float cb = cdf[below], ca = cdf[above];
        float bb = dcoarse_at(below), ba = dcoarse_at(above);
        float denom = ca - cb;
        if (denom < 1e-5f) denom = 1.0f;
        float t = (uu - cb) / denom;
        sortbuf[NC + tid] = bb + t * (ba - bb);
    }
    if (tid < NC) sortbuf[tid] = dcoarse_at(tid);
    if (tid >= NALL) sortbuf[tid] = INFINITY;
    __syncthreads();
    for (int k = 2; k <= 256; k <<= 1) {
        for (int j = k >> 1; j > 0; j >>= 1) {
            int ixj = tid ^ j;
            if (ixj > tid) {
                float a = sortbuf[tid], b = sortbuf[ixj];
                bool up = ((tid & k) == 0);
                if (up ? (a > b) : (a < b)) {
                    sortbuf[tid] = b;
                    sortbuf[ixj] = a;
                }
            }
            __syncthreads();
        }
    }
    if (tid < NALL) d_all[ray * NALL + tid] = sortbuf[tid];
}

// Per-ray sdf_to_w on merged set, occu sum, out = 1-occu.
__global__ __launch_bounds__(192) void finish_kernel(
    const float* __restrict__ sdf_a, float* __restrict__ out) {
    int ray = blockIdx.x;
    int tid = threadIdx.x;
    __shared__ float csig[NALL];
    if (tid < NALL) {
        float s = sdf_a[ray * NALL + tid];
        csig[tid] = 1.0f / (1.0f + expf(-100.0f * s));
    }
    __syncthreads();
    if (tid == 0) {
        float T = 1.0f, occu = 0.0f;
        for (int i = 0; i < NALL - 1; ++i) {
            float a = fmaxf((csig[i] - csig[i + 1]) / (csig[i] + 1e-10f), 0.0f);
            occu += a * T;
            T *= (1.0f - a + 1e-10f);
        }
        out[ray] = 1.0f - occu;
    }
}

extern "C" void kernel_launch(void* const* d_in, const int* in_sizes, int n_in,
                              void* d_out, int out_size, void* d_ws, size_t ws_size,
                              hipStream_t stream) {
    const float* pts = (const float*)d_in[0];
    const float* lights = (const float*)d_in[1];
    const float* u = (const float*)d_in[2];
    const float* w0 = (const float*)d_in[3];
    const float* b0 = (const float*)d_in[4];
    const float* w1 = (const float*)d_in[5];
    const float* b1 = (const float*)d_in[6];
    const float* w2 = (const float*)d_in[7];
    const float* b2 = (const float*)d_in[8];
    const float* w3 = (const float*)d_in[9];
    const float* b3 = (const float*)d_in[10];
    float* out = (float*)d_out;

    float* ws = (float*)d_ws;
    float* d_all = ws;                          // NRAY*NALL
    float* sdf = ws + (size_t)NRAY * NALL;      // NRAY*NALL (coarse uses first NRAY*NC)

    mlp_kernel<0><<<(NRAY * NC) / MT, THREADS, 0, stream>>>(
        pts, lights, nullptr, w0, b0, w1, b1, w2, b2, w3, b3, sdf);
    sample_kernel<<<NRAY, 256, 0, stream>>>(sdf, u, d_all);
    mlp_kernel<1><<<(NRAY * NALL) / MT, THREADS, 0, stream>>>(
        pts, lights, d_all, w0, b0, w1, b1, w2, b2, w3, b3, sdf);
    finish_kernel<<<NRAY, 192, 0, stream>>>(sdf, out);
}

// Round 3
// 498.702 us; speedup vs baseline: 13.8675x; 1.7067x over previous
//
#include <hip/hip_runtime.h>
#include <math.h>

#define NL 8
#define NP 512
#define NC 64
#define NF 128
#define NALL 192
#define NRAY (NL * NP)
#define HID 128
#define HPAD 136   // H row stride in halves: conflict-free b128 phases

typedef _Float16 half8 __attribute__((ext_vector_type(8)));
typedef _Float16 half4v __attribute__((ext_vector_type(4)));
typedef float floatx16 __attribute__((ext_vector_type(16)));

#define MFMA(a, b, c) __builtin_amdgcn_mfma_f32_32x32x16_f16((a), (b), (c), 0, 0, 0)

__device__ __forceinline__ float dcoarse_at(int i) {
    float t = (float)i * 0.015625f; // i/64, exact in fp32
    return 1e-3f * (1.0f - t) + 0.5f * t;
}

__device__ __forceinline__ floatx16 fzero16() {
    floatx16 z;
#pragma unroll
    for (int i = 0; i < 16; ++i) z[i] = 0.f;
    return z;
}
__device__ __forceinline__ half8 hzero8() {
    half8 z;
#pragma unroll
    for (int i = 0; i < 8; ++i) z[i] = (_Float16)0.f;
    return z;
}

// Pre-transpose + split weights: Wsp[(layer*2+hl)*16384 + j*128 + k]
// layer 0 = w1, layer 1 = w2;  value = w[k*128+j] split into fp16 hi/lo.
__global__ void prep_kernel(const float* __restrict__ w1, const float* __restrict__ w2,
                            _Float16* __restrict__ Wsp) {
    int j = blockIdx.x, layer = blockIdx.y, k = threadIdx.x;
    const float* w = layer ? w2 : w1;
    float v = w[k * 128 + j];
    _Float16 hi = (_Float16)v;
    Wsp[(layer * 2 + 0) * 16384 + j * 128 + k] = hi;
    Wsp[(layer * 2 + 1) * 16384 + j * 128 + k] = (_Float16)(v - (float)hi);
}

// Fused 4-layer MLP over 128 points per block, split-fp16 MFMA.
// Waves: (jh = w&1) owns j-half (2 j-tiles of 32), (mh = w>>1) owns m-half (2 m-tiles).
// H (activations) in LDS as hi/lo planes [m][k], stride HPAD.
// A (weights^T) resident in VGPRs per wave (hi/lo, 2jt x 8ks x half8 = 128 VGPR).
template<int MODE, int FASTW>   // MODE 0: coarse (d computed), 1: fine (d from d_all)
__global__ __launch_bounds__(256, 2) void mlp_kernel(
    const float* __restrict__ pts, const float* __restrict__ lights,
    const float* __restrict__ d_all,
    const float* __restrict__ w0, const float* __restrict__ b0,
    const float* __restrict__ w1, const float* __restrict__ b1,
    const float* __restrict__ w2, const float* __restrict__ b2,
    const float* __restrict__ w3, const float* __restrict__ b3,
    const _Float16* __restrict__ Wsp,
    float* __restrict__ sdf_out)
{
    __shared__ __align__(16) _Float16 Hhi[128 * HPAD];
    __shared__ __align__(16) _Float16 Hlo[128 * HPAD];
    __shared__ _Float16 Xs[6 * 128];  // hi c0,c1,c2 then lo c0,c1,c2
    __shared__ float P2[256];         // [jh][m]

    const int tid = threadIdx.x;
    const int lane = tid & 63;
    const int wv = tid >> 6;
    const int jh = wv & 1, mh = wv >> 1;
    const int l31 = lane & 31, lhi = lane >> 5;
    const int base = blockIdx.x * 128;

    // ---- phase A: per-point coords, split to fp16 hi/lo in LDS
    if (tid < 128) {
        int pt = base + tid;
        int ray; float d;
        if (MODE == 0) { ray = pt >> 6; d = dcoarse_at(pt & 63); }
        else           { ray = (int)((unsigned)pt / 192u); d = d_all[pt]; }
        int l = ray >> 9, p = ray & (NP - 1);
        float px = pts[p * 3 + 0], py = pts[p * 3 + 1], pz = pts[p * 3 + 2];
        float dx = lights[l * 3 + 0] - px, dy = lights[l * 3 + 1] - py, dz = lights[l * 3 + 2] - pz;
        float n = sqrtf(dx * dx + dy * dy + dz * dz);
        dx /= n; dy /= n; dz /= n;
        float xc[3] = { px + d * dx, py + d * dy, pz + d * dz };
#pragma unroll
        for (int c = 0; c < 3; ++c) {
            _Float16 h = (_Float16)xc[c];
            Xs[c * 128 + tid] = h;
            Xs[(3 + c) * 128 + tid] = (_Float16)(xc[c] - (float)h);
        }
    }
    __syncthreads();

    // epilogue helper: bias+relu+split, write tile rows to H
    auto store_tile = [&](const floatx16& a, int jt, int m, const float* __restrict__ bias) {
#pragma unroll
        for (int g = 0; g < 4; ++g) {
            int jg = jh * 64 + jt * 32 + 8 * g + 4 * lhi;
            half4v hq, lq;
#pragma unroll
            for (int q = 0; q < 4; ++q) {
                float v = a[g * 4 + q] + bias[jg + q];
                v = fmaxf(v, 0.f);
                _Float16 hi = (_Float16)v;
                hq[q] = hi;
                lq[q] = (_Float16)(v - (float)hi);
            }
            *(half4v*)&Hhi[m * HPAD + jg] = hq;
            *(half4v*)&Hlo[m * HPAD + jg] = lq;
        }
    };

    // ---- Layer 1: 3->128 as one K=16 MFMA step (k>=3 zero-padded)
    {
        half8 a1h[2], a1l[2];
#pragma unroll
        for (int jt = 0; jt < 2; ++jt) { a1h[jt] = hzero8(); a1l[jt] = hzero8(); }
        if (lhi == 0) {
#pragma unroll
            for (int jt = 0; jt < 2; ++jt) {
                int j = jh * 64 + jt * 32 + l31;
#pragma unroll
                for (int c = 0; c < 3; ++c) {
                    float v = w0[c * 128 + j];
                    _Float16 hi = (_Float16)v;
                    a1h[jt][c] = hi;
                    a1l[jt][c] = (_Float16)(v - (float)hi);
                }
            }
        }
        floatx16 acc[2][2];
#pragma unroll
        for (int mt = 0; mt < 2; ++mt)
#pragma unroll
            for (int jt = 0; jt < 2; ++jt) acc[mt][jt] = fzero16();
#pragma unroll
        for (int mt = 0; mt < 2; ++mt) {
            half8 bh = hzero8(), bl = hzero8();
            if (lhi == 0) {
                int m = mh * 64 + mt * 32 + l31;
#pragma unroll
                for (int c = 0; c < 3; ++c) { bh[c] = Xs[c * 128 + m]; bl[c] = Xs[(3 + c) * 128 + m]; }
            }
#pragma unroll
            for (int jt = 0; jt < 2; ++jt) {
                acc[mt][jt] = MFMA(a1l[jt], bh, acc[mt][jt]);
                acc[mt][jt] = MFMA(a1h[jt], bl, acc[mt][jt]);
                acc[mt][jt] = MFMA(a1h[jt], bh, acc[mt][jt]);
            }
        }
#pragma unroll
        for (int mt = 0; mt < 2; ++mt) {
            int m = mh * 64 + mt * 32 + l31;
#pragma unroll
            for (int jt = 0; jt < 2; ++jt) store_tile(acc[mt][jt], jt, m, b0);
        }
    }
    __syncthreads();

    // A-fragment loader (weights^T, hi/lo): resident per wave
    half8 ah[2][8], al[2][8];
    auto load_A = [&](const float* __restrict__ w,
                      const _Float16* __restrict__ whi, const _Float16* __restrict__ wlo) {
#pragma unroll
        for (int jt = 0; jt < 2; ++jt) {
            int j = jh * 64 + jt * 32 + l31;
#pragma unroll
            for (int ks = 0; ks < 8; ++ks) {
                int k0 = ks * 16 + lhi * 8;
                if (FASTW) {
                    ah[jt][ks] = *(const half8*)&whi[j * 128 + k0];
                    al[jt][ks] = *(const half8*)&wlo[j * 128 + k0];
                } else {
#pragma unroll
                    for (int i = 0; i < 8; ++i) {
                        float v = w[(k0 + i) * 128 + j];
                        _Float16 hi = (_Float16)v;
                        ah[jt][ks][i] = hi;
                        al[jt][ks][i] = (_Float16)(v - (float)hi);
                    }
                }
            }
        }
    };

    // ---- Layer 2: H1 -> H2 (in place by row-quadrant, barriered)
    load_A(w1, Wsp + 0, Wsp + 16384);
#pragma unroll
    for (int mt = 0; mt < 2; ++mt) {
        int m = mh * 64 + mt * 32 + l31;
        floatx16 acc[2];
        acc[0] = fzero16(); acc[1] = fzero16();
#pragma unroll
        for (int ks = 0; ks < 8; ++ks) {
            int off = m * HPAD + ks * 16 + lhi * 8;
            half8 bh = *(const half8*)&Hhi[off];
            half8 bl = *(const half8*)&Hlo[off];
#pragma unroll
            for (int jt = 0; jt < 2; ++jt) {
                acc[jt] = MFMA(al[jt][ks], bh, acc[jt]);
                acc[jt] = MFMA(ah[jt][ks], bl, acc[jt]);
                acc[jt] = MFMA(ah[jt][ks], bh, acc[jt]);
            }
        }
        __syncthreads();   // all waves done reading rows mt
#pragma unroll
        for (int jt = 0; jt < 2; ++jt) store_tile(acc[jt], jt, m, b1);
        __syncthreads();   // writes visible before next phase reads
    }

    // ---- Layer 3 + Layer 4 reduce (no H write-back)
    load_A(w2, Wsp + 32768, Wsp + 49152);
#pragma unroll
    for (int mt = 0; mt < 2; ++mt) {
        int m = mh * 64 + mt * 32 + l31;
        floatx16 acc[2];
        acc[0] = fzero16(); acc[1] = fzero16();
#pragma unroll
        for (int ks = 0; ks < 8; ++ks) {
            int off = m * HPAD + ks * 16 + lhi * 8;
            half8 bh = *(const half8*)&Hhi[off];
            half8 bl = *(const half8*)&Hlo[off];
#pragma unroll
            for (int jt = 0; jt < 2; ++jt) {
                acc[jt] = MFMA(al[jt][ks], bh, acc[jt]);
                acc[jt] = MFMA(ah[jt][ks], bl, acc[jt]);
                acc[jt] = MFMA(ah[jt][ks], bh, acc[jt]);
            }
        }
        float p = 0.f;
#pragma unroll
        for (int jt = 0; jt < 2; ++jt)
#pragma unroll
            for (int g = 0; g < 4; ++g) {
                int jg = jh * 64 + jt * 32 + 8 * g + 4 * lhi;
#pragma unroll
                for (int q = 0; q < 4; ++q) {
                    float v = fmaxf(acc[jt][g * 4 + q] + b2[jg + q], 0.f);
                    p = fmaf(v, w3[jg + q], p);
                }
            }
        p += __shfl_xor(p, 32);
        if (lane < 32) P2[jh * 128 + mh * 64 + mt * 32 + l31] = p;
    }
    __syncthreads();
    if (tid < 128) sdf_out[base + tid] = b3[0] + P2[tid] + P2[128 + tid];
}

// Per-ray: sdf_to_w on coarse, sample_pdf (exact searchsorted-count semantics),
// then bitonic sort of coarse+fine (padded to 256 with +inf).
__global__ __launch_bounds__(256) void sample_kernel(
    const float* __restrict__ sdf_c, const float* __restrict__ u,
    float* __restrict__ d_all) {
    int ray = blockIdx.x;
    int tid = threadIdx.x;
    __shared__ float csig[NC];
    __shared__ float alpha[NC - 1];
    __shared__ float wbuf[NC - 1];
    __shared__ float cdf[NC];
    __shared__ float sortbuf[256];

    if (tid < NC) {
        float s = sdf_c[ray * NC + tid];
        csig[tid] = 1.0f / (1.0f + expf(-100.0f * s));
    }
    __syncthreads();
    if (tid < NC - 1) {
        float a = (csig[tid] - csig[tid + 1]) / (csig[tid] + 1e-10f);
        alpha[tid] = fmaxf(a, 0.0f);
    }
    __syncthreads();
    if (tid == 0) {
        float T = 1.0f, wsum = 0.0f;
        for (int i = 0; i < NC - 1; ++i) {
            float w = alpha[i] * T + 1e-5f;
            wbuf[i] = w;
            wsum += w;
            T *= (1.0f - alpha[i] + 1e-10f);
        }
        float c = 0.0f;
        cdf[0] = 0.0f;
        for (int i = 0; i < NC - 1; ++i) {
            c += wbuf[i] / wsum;
            cdf[i + 1] = c;
        }
    }
    __syncthreads();
    if (tid < NF) {
        float uu = u[ray * NF + tid];
        int inds = 0;
        for (int j = 0; j < NC; ++j) inds += (uu >= cdf[j]) ? 1 : 0;
        int below = min(max(inds - 1, 0), NC - 1);
        int above = min(inds, NC - 1);
        float cb = cdf[below], ca = cdf[above];
        float bb = dcoarse_at(below), ba = dcoarse_at(above);
        float denom = ca - cb;
        if (denom < 1e-5f) denom = 1.0f;
        float t = (uu - cb) / denom;
        sortbuf[NC + tid] = bb + t * (ba - bb);
    }
    if (tid < NC) sortbuf[tid] = dcoarse_at(tid);
    if (tid >= NALL) sortbuf[tid] = INFINITY;
    __syncthreads();
    for (int k = 2; k <= 256; k <<= 1) {
        for (int j = k >> 1; j > 0; j >>= 1) {
            int ixj = tid ^ j;
            if (ixj > tid) {
                float a = sortbuf[tid], b = sortbuf[ixj];
                bool up = ((tid & k) == 0);
                if (up ? (a > b) : (a < b)) {
                    sortbuf[tid] = b;
                    sortbuf[ixj] = a;
                }
            }
            __syncthreads();
        }
    }
    if (tid < NALL) d_all[ray * NALL + tid] = sortbuf[tid];
}

// Per-ray sdf_to_w on merged set, occu sum, out = 1-occu.
__global__ __launch_bounds__(192) void finish_kernel(
    const float* __restrict__ sdf_a, float* __restrict__ out) {
    int ray = blockIdx.x;
    int tid = threadIdx.x;
    __shared__ float csig[NALL];
    if (tid < NALL) {
        float s = sdf_a[ray * NALL + tid];
        csig[tid] = 1.0f / (1.0f + expf(-100.0f * s));
    }
    __syncthreads();
    if (tid == 0) {
        float T = 1.0f, occu = 0.0f;
        for (int i = 0; i < NALL - 1; ++i) {
            float a = fmaxf((csig[i] - csig[i + 1]) / (csig[i] + 1e-10f), 0.0f);
            occu += a * T;
            T *= (1.0f - a + 1e-10f);
        }
        out[ray] = 1.0f - occu;
    }
}

extern "C" void kernel_launch(void* const* d_in, const int* in_sizes, int n_in,
                              void* d_out, int out_size, void* d_ws, size_t ws_size,
                              hipStream_t stream) {
    const float* pts = (const float*)d_in[0];
    const float* lights = (const float*)d_in[1];
    const float* u = (const float*)d_in[2];
    const float* w0 = (const float*)d_in[3];
    const float* b0 = (const float*)d_in[4];
    const float* w1 = (const float*)d_in[5];
    const float* b1 = (const float*)d_in[6];
    const float* w2 = (const float*)d_in[7];
    const float* b2 = (const float*)d_in[8];
    const float* w3 = (const float*)d_in[9];
    const float* b3 = (const float*)d_in[10];
    float* out = (float*)d_out;

    float* ws = (float*)d_ws;
    float* d_all = ws;                          // NRAY*NALL
    float* sdf = ws + (size_t)NRAY * NALL;      // NRAY*NALL (coarse uses first NRAY*NC)

    const size_t base_bytes = (size_t)2 * NRAY * NALL * 4;
    const bool fast = ws_size >= base_bytes + 4 * 16384 * sizeof(_Float16);
    _Float16* Wsp = (_Float16*)((char*)d_ws + base_bytes);

    if (fast) {
        prep_kernel<<<dim3(128, 2), 128, 0, stream>>>(w1, w2, Wsp);
        mlp_kernel<0, 1><<<(NRAY * NC) / 128, 256, 0, stream>>>(
            pts, lights, nullptr, w0, b0, w1, b1, w2, b2, w3, b3, Wsp, sdf);
        sample_kernel<<<NRAY, 256, 0, stream>>>(sdf, u, d_all);
        mlp_kernel<1, 1><<<(NRAY * NALL) / 128, 256, 0, stream>>>(
            pts, lights, d_all, w0, b0, w1, b1, w2, b2, w3, b3, Wsp, sdf);
    } else {
        mlp_kernel<0, 0><<<(NRAY * NC) / 128, 256, 0, stream>>>(
            pts, lights, nullptr, w0, b0, w1, b1, w2, b2, w3, b3, nullptr, sdf);
        sample_kernel<<<NRAY, 256, 0, stream>>>(sdf, u, d_all);
        mlp_kernel<1, 0><<<(NRAY * NALL) / 128, 256, 0, stream>>>(
            pts, lights, d_all, w0, b0, w1, b1, w2, b2, w3, b3, nullptr, sdf);
    }
    finish_kernel<<<NRAY, 192, 0, stream>>>(sdf, out);
}

// Round 4
// 320.712 us; speedup vs baseline: 21.5638x; 1.5550x over previous
//
#include <hip/hip_runtime.h>
#include <math.h>

#define NL 8
#define NP 512
#define NC 64
#define NF 128
#define NALL 192
#define NRAY (NL * NP)
#define HID 128

typedef _Float16 half8 __attribute__((ext_vector_type(8)));
typedef _Float16 half4v __attribute__((ext_vector_type(4)));
typedef float floatx16 __attribute__((ext_vector_type(16)));

#define MFMA(a, b, c) __builtin_amdgcn_mfma_f32_32x32x16_f16((a), (b), (c), 0, 0, 0)

__device__ __forceinline__ float dcoarse_at(int i) {
    float t = (float)i * 0.015625f; // i/64, exact in fp32
    return 1e-3f * (1.0f - t) + 0.5f * t;
}

__device__ __forceinline__ floatx16 fzero16() {
    floatx16 z;
#pragma unroll
    for (int i = 0; i < 16; ++i) z[i] = 0.f;
    return z;
}
__device__ __forceinline__ half8 hzero8() {
    half8 z;
#pragma unroll
    for (int i = 0; i < 8; ++i) z[i] = (_Float16)0.f;
    return z;
}

// Wsp layout (per layer L in {0:w1, 1:w2}, plane p in {hi,lo}):
//   Wsp[(L*2+p)*16384 + f],  f = (((jb*8+ks)*2+lhi)*32 + l31)*8 + i
//   holding split(w[(ks*16+lhi*8+i)*128 + (jb*32+l31)]).
// One A-fragment (jb,ks) = 1 KB contiguous -> fully coalesced wave load.
__global__ void prep_kernel(const float* __restrict__ w1, const float* __restrict__ w2,
                            _Float16* __restrict__ Wsp) {
    int f = blockIdx.x * 256 + threadIdx.x;   // [0, 16384)
    int layer = blockIdx.y;
    const float* w = layer ? w2 : w1;
    int i = f & 7, l31 = (f >> 3) & 31, lhi = (f >> 8) & 1, ks = (f >> 9) & 7, jb = f >> 12;
    int j = jb * 32 + l31;
    int k = ks * 16 + lhi * 8 + i;
    float v = w[k * 128 + j];
    _Float16 hi = (_Float16)v;
    Wsp[(layer * 2 + 0) * 16384 + f] = hi;
    Wsp[(layer * 2 + 1) * 16384 + f] = (_Float16)(v - (float)hi);
}

// Fused 4-layer MLP over 64 points per block, split-fp16 MFMA.
// 4 waves: jh = wv&1 (j-half of 64), mh = wv>>1 (m-tile of 32).
// H planes in LDS, XOR-swizzled (no padding, conflict-free b128 phases).
// B (activations) layer-resident in regs; A (weights) streamed coalesced from Wsp.
template<int MODE, int FASTW>   // MODE 0: coarse (d computed), 1: fine (d from d_all)
__global__ __launch_bounds__(256, 3) void mlp_kernel(
    const float* __restrict__ pts, const float* __restrict__ lights,
    const float* __restrict__ d_all,
    const float* __restrict__ w0, const float* __restrict__ b0,
    const float* __restrict__ w1, const float* __restrict__ b1,
    const float* __restrict__ w2, const float* __restrict__ b2,
    const float* __restrict__ w3, const float* __restrict__ b3,
    const _Float16* __restrict__ Wsp,
    float* __restrict__ sdf_out)
{
    __shared__ __align__(16) _Float16 Hhi[64 * 128];
    __shared__ __align__(16) _Float16 Hlo[64 * 128];
    __shared__ _Float16 Xs[6 * 64];   // hi c0,c1,c2 then lo c0,c1,c2
    __shared__ float P2[128];         // [jh][m]

    const int tid = threadIdx.x;
    const int lane = tid & 63;
    const int wv = tid >> 6;
    const int jh = wv & 1, mh = wv >> 1;
    const int l31 = lane & 31, lhi = lane >> 5;
    const int base = blockIdx.x * 64;

    // ---- phase A: per-point coords, split to fp16 hi/lo in LDS
    if (tid < 64) {
        int pt = base + tid;
        int ray; float d;
        if (MODE == 0) { ray = pt >> 6; d = dcoarse_at(pt & 63); }
        else           { ray = (int)((unsigned)pt / 192u); d = d_all[pt]; }
        int l = ray >> 9, p = ray & (NP - 1);
        float px = pts[p * 3 + 0], py = pts[p * 3 + 1], pz = pts[p * 3 + 2];
        float dx = lights[l * 3 + 0] - px, dy = lights[l * 3 + 1] - py, dz = lights[l * 3 + 2] - pz;
        float n = sqrtf(dx * dx + dy * dy + dz * dz);
        dx /= n; dy /= n; dz /= n;
        float xc[3] = { px + d * dx, py + d * dy, pz + d * dz };
#pragma unroll
        for (int c = 0; c < 3; ++c) {
            _Float16 h = (_Float16)xc[c];
            Xs[c * 64 + tid] = h;
            Xs[(3 + c) * 64 + tid] = (_Float16)(xc[c] - (float)h);
        }
    }
    __syncthreads();

    const int m = mh * 32 + l31;   // this lane's point (MFMA C column)
    const int msw = m & 7;

    // swizzled H address (halves) for element (m, k): kblk = k>>4, jo = k&15
    auto haddr = [&](int kblk, int jo) { return m * 128 + (((kblk ^ msw) << 4) + jo); };

    // epilogue helper: bias+relu+split, write C tile to H (this lane's column m)
    auto store_tile = [&](const floatx16& a, int jt, const float* __restrict__ bias) {
#pragma unroll
        for (int g = 0; g < 4; ++g) {
            int jg = jh * 64 + jt * 32 + 8 * g + 4 * lhi;
            half4v hq, lq;
#pragma unroll
            for (int q = 0; q < 4; ++q) {
                float v = fmaxf(a[g * 4 + q] + bias[jg + q], 0.f);
                _Float16 hi = (_Float16)v;
                hq[q] = hi;
                lq[q] = (_Float16)(v - (float)hi);
            }
            int ad = haddr(jg >> 4, jg & 15);
            *(half4v*)&Hhi[ad] = hq;
            *(half4v*)&Hlo[ad] = lq;
        }
    };

    // ---- Layer 1: 3->128 as one K=16 MFMA step (k>=3 zero-padded)
    {
        half8 a1h[2], a1l[2], bh1, bl1;
#pragma unroll
        for (int jt = 0; jt < 2; ++jt) { a1h[jt] = hzero8(); a1l[jt] = hzero8(); }
        bh1 = hzero8(); bl1 = hzero8();
        if (lhi == 0) {
#pragma unroll
            for (int jt = 0; jt < 2; ++jt) {
                int j = jh * 64 + jt * 32 + l31;
#pragma unroll
                for (int c = 0; c < 3; ++c) {
                    float v = w0[c * 128 + j];
                    _Float16 hi = (_Float16)v;
                    a1h[jt][c] = hi;
                    a1l[jt][c] = (_Float16)(v - (float)hi);
                }
            }
#pragma unroll
            for (int c = 0; c < 3; ++c) { bh1[c] = Xs[c * 64 + m]; bl1[c] = Xs[(3 + c) * 64 + m]; }
        }
        floatx16 acc0 = fzero16(), acc1 = fzero16();
        acc0 = MFMA(a1l[0], bh1, acc0);
        acc1 = MFMA(a1l[1], bh1, acc1);
        acc0 = MFMA(a1h[0], bl1, acc0);
        acc1 = MFMA(a1h[1], bl1, acc1);
        acc0 = MFMA(a1h[0], bh1, acc0);
        acc1 = MFMA(a1h[1], bh1, acc1);
        store_tile(acc0, 0, b0);
        store_tile(acc1, 1, b0);
    }
    __syncthreads();

    // streamed A-fragment loader (coalesced 1 KB per fragment in FASTW mode)
    auto ldA = [&](int L, int jt, int ks, half8& ah, half8& al) {
        if (FASTW) {
            int off = ((((jh * 2 + jt) * 8 + ks) * 2 + lhi) * 32 + l31) * 8;
            ah = *(const half8*)&Wsp[(L * 2 + 0) * 16384 + off];
            al = *(const half8*)&Wsp[(L * 2 + 1) * 16384 + off];
        } else {
            const float* w = L ? w2 : w1;
            int j = jh * 64 + jt * 32 + l31, k0 = ks * 16 + lhi * 8;
#pragma unroll
            for (int i = 0; i < 8; ++i) {
                float v = w[(k0 + i) * 128 + j];
                _Float16 hi = (_Float16)v;
                ah[i] = hi;
                al[i] = (_Float16)(v - (float)hi);
            }
        }
    };

    half8 bh[8], bl[8];
    floatx16 acc[2];

    // ---- Layer 2: H1 -> H2
#pragma unroll
    for (int ks = 0; ks < 8; ++ks) {
        int ad = haddr(ks, lhi * 8);
        bh[ks] = *(const half8*)&Hhi[ad];
        bl[ks] = *(const half8*)&Hlo[ad];
    }
    acc[0] = fzero16(); acc[1] = fzero16();
#pragma unroll
    for (int ks = 0; ks < 8; ++ks) {
        half8 ah0, al0, ah1, al1;
        ldA(0, 0, ks, ah0, al0);
        ldA(0, 1, ks, ah1, al1);
        acc[0] = MFMA(al0, bh[ks], acc[0]);
        acc[1] = MFMA(al1, bh[ks], acc[1]);
        acc[0] = MFMA(ah0, bl[ks], acc[0]);
        acc[1] = MFMA(ah1, bl[ks], acc[1]);
        acc[0] = MFMA(ah0, bh[ks], acc[0]);
        acc[1] = MFMA(ah1, bh[ks], acc[1]);
    }
    __syncthreads();   // all waves done reading H1
    store_tile(acc[0], 0, b1);
    store_tile(acc[1], 1, b1);
    __syncthreads();   // H2 visible

    // ---- Layer 3 (+ Layer 4 reduce, no write-back)
#pragma unroll
    for (int ks = 0; ks < 8; ++ks) {
        int ad = haddr(ks, lhi * 8);
        bh[ks] = *(const half8*)&Hhi[ad];
        bl[ks] = *(const half8*)&Hlo[ad];
    }
    acc[0] = fzero16(); acc[1] = fzero16();
#pragma unroll
    for (int ks = 0; ks < 8; ++ks) {
        half8 ah0, al0, ah1, al1;
        ldA(1, 0, ks, ah0, al0);
        ldA(1, 1, ks, ah1, al1);
        acc[0] = MFMA(al0, bh[ks], acc[0]);
        acc[1] = MFMA(al1, bh[ks], acc[1]);
        acc[0] = MFMA(ah0, bl[ks], acc[0]);
        acc[1] = MFMA(ah1, bl[ks], acc[1]);
        acc[0] = MFMA(ah0, bh[ks], acc[0]);
        acc[1] = MFMA(ah1, bh[ks], acc[1]);
    }
    float p = 0.f;
#pragma unroll
    for (int jt = 0; jt < 2; ++jt)
#pragma unroll
        for (int g = 0; g < 4; ++g) {
            int jg = jh * 64 + jt * 32 + 8 * g + 4 * lhi;
#pragma unroll
            for (int q = 0; q < 4; ++q) {
                float v = fmaxf(acc[jt][g * 4 + q] + b2[jg + q], 0.f);
                p = fmaf(v, w3[jg + q], p);
            }
        }
    p += __shfl_xor(p, 32);
    if (lane < 32) P2[jh * 64 + mh * 32 + l31] = p;
    __syncthreads();
    if (tid < 64) sdf_out[base + tid] = b3[0] + P2[tid] + P2[64 + tid];
}

// Per-ray: sdf_to_w on coarse (wave-parallel scans), sample_pdf (exact
// searchsorted-count semantics), then bitonic sort (padded to 256 with +inf).
__global__ __launch_bounds__(256) void sample_kernel(
    const float* __restrict__ sdf_c, const float* __restrict__ u,
    float* __restrict__ d_all) {
    int ray = blockIdx.x;
    int tid = threadIdx.x;
    __shared__ float cdf[NC];
    __shared__ float sortbuf[256];

    if (tid < 64) {   // wave 0: sigmoid -> alpha -> T (product scan) -> w -> cdf (add scan)
        int i = tid;
        float sv = sdf_c[ray * NC + i];
        float c = 1.0f / (1.0f + expf(-100.0f * sv));
        float cn = __shfl_down(c, 1);
        bool valid = i < 63;
        float a = valid ? fmaxf((c - cn) / (c + 1e-10f), 0.f) : 0.f;
        float sh = valid ? (1.f - a + 1e-10f) : 1.f;
        float ps = sh;
#pragma unroll
        for (int off = 1; off < 64; off <<= 1) { float o = __shfl_up(ps, off); if (i >= off) ps *= o; }
        float T = __shfl_up(ps, 1);
        if (i == 0) T = 1.f;
        float w = valid ? (a * T + 1e-5f) : 0.f;
        float wsum = w;
#pragma unroll
        for (int off = 1; off < 64; off <<= 1) wsum += __shfl_xor(wsum, off);
        float pdf = w / wsum;
        float cs = pdf;
#pragma unroll
        for (int off = 1; off < 64; off <<= 1) { float o = __shfl_up(cs, off); if (i >= off) cs += o; }
        if (i == 0) cdf[0] = 0.f;
        if (valid) cdf[i + 1] = cs;
    }
    __syncthreads();
    if (tid < NF) {
        float uu = u[ray * NF + tid];
        int inds = 0;
        for (int j = 0; j < NC; ++j) inds += (uu >= cdf[j]) ? 1 : 0;
        int below = min(max(inds - 1, 0), NC - 1);
        int above = min(inds, NC - 1);
        float cb = cdf[below], ca = cdf[above];
        float bb = dcoarse_at(below), ba = dcoarse_at(above);
        float denom = ca - cb;
        if (denom < 1e-5f) denom = 1.0f;
        float t = (uu - cb) / denom;
        sortbuf[NC + tid] = bb + t * (ba - bb);
    }
    if (tid < NC) sortbuf[tid] = dcoarse_at(tid);
    if (tid >= NALL) sortbuf[tid] = INFINITY;
    __syncthreads();
    for (int k = 2; k <= 256; k <<= 1) {
        for (int j = k >> 1; j > 0; j >>= 1) {
            int ixj = tid ^ j;
            if (ixj > tid) {
                float a = sortbuf[tid], b = sortbuf[ixj];
                bool up = ((tid & k) == 0);
                if (up ? (a > b) : (a < b)) {
                    sortbuf[tid] = b;
                    sortbuf[ixj] = a;
                }
            }
            __syncthreads();
        }
    }
    if (tid < NALL) d_all[ray * NALL + tid] = sortbuf[tid];
}

// One wave per ray: chunked (3/lane) product scan for T, occu sum, out = 1-occu.
__global__ __launch_bounds__(256) void finish_kernel(
    const float* __restrict__ sdf_a, float* __restrict__ out) {
    int lane = threadIdx.x & 63, wv = threadIdx.x >> 6;
    int ray = blockIdx.x * 4 + wv;
    const float* S = sdf_a + (size_t)ray * NALL;
    float c[4];
#pragma unroll
    for (int t = 0; t < 4; ++t) {
        int i = lane * 3 + t;
        c[t] = (i < NALL) ? 1.0f / (1.0f + expf(-100.0f * S[i])) : 0.f;
    }
    float a[3], s[3];
#pragma unroll
    for (int t = 0; t < 3; ++t) {
        int i = lane * 3 + t;
        if (i < NALL - 1) {
            a[t] = fmaxf((c[t] - c[t + 1]) / (c[t] + 1e-10f), 0.f);
            s[t] = 1.f - a[t] + 1e-10f;
        } else { a[t] = 0.f; s[t] = 1.f; }
    }
    float chunk = s[0] * s[1] * s[2];
    float ps = chunk;
#pragma unroll
    for (int off = 1; off < 64; off <<= 1) {
        float o = __shfl_up(ps, off);
        if (lane >= off) ps *= o;
    }
    float T = __shfl_up(ps, 1);
    if (lane == 0) T = 1.f;
    float occ = a[0] * T;
    T *= s[0]; occ = fmaf(a[1], T, occ);
    T *= s[1]; occ = fmaf(a[2], T, occ);
#pragma unroll
    for (int off = 1; off < 64; off <<= 1) occ += __shfl_xor(occ, off);
    if (lane == 0) out[ray] = 1.f - occ;
}

extern "C" void kernel_launch(void* const* d_in, const int* in_sizes, int n_in,
                              void* d_out, int out_size, void* d_ws, size_t ws_size,
                              hipStream_t stream) {
    const float* pts = (const float*)d_in[0];
    const float* lights = (const float*)d_in[1];
    const float* u = (const float*)d_in[2];
    const float* w0 = (const float*)d_in[3];
    const float* b0 = (const float*)d_in[4];
    const float* w1 = (const float*)d_in[5];
    const float* b1 = (const float*)d_in[6];
    const float* w2 = (const float*)d_in[7];
    const float* b2 = (const float*)d_in[8];
    const float* w3 = (const float*)d_in[9];
    const float* b3 = (const float*)d_in[10];
    float* out = (float*)d_out;

    float* ws = (float*)d_ws;
    float* d_all = ws;                          // NRAY*NALL
    float* sdf = ws + (size_t)NRAY * NALL;      // NRAY*NALL (coarse uses first NRAY*NC)

    const size_t base_bytes = (size_t)2 * NRAY * NALL * 4;
    const bool fast = ws_size >= base_bytes + 4 * 16384 * sizeof(_Float16);
    _Float16* Wsp = (_Float16*)((char*)d_ws + base_bytes);

    if (fast) {
        prep_kernel<<<dim3(64, 2), 256, 0, stream>>>(w1, w2, Wsp);
        mlp_kernel<0, 1><<<(NRAY * NC) / 64, 256, 0, stream>>>(
            pts, lights, nullptr, w0, b0, w1, b1, w2, b2, w3, b3, Wsp, sdf);
        sample_kernel<<<NRAY, 256, 0, stream>>>(sdf, u, d_all);
        mlp_kernel<1, 1><<<(NRAY * NALL) / 64, 256, 0, stream>>>(
            pts, lights, d_all, w0, b0, w1, b1, w2, b2, w3, b3, Wsp, sdf);
    } else {
        mlp_kernel<0, 0><<<(NRAY * NC) / 64, 256, 0, stream>>>(
            pts, lights, nullptr, w0, b0, w1, b1, w2, b2, w3, b3, nullptr, sdf);
        sample_kernel<<<NRAY, 256, 0, stream>>>(sdf, u, d_all);
        mlp_kernel<1, 0><<<(NRAY * NALL) / 64, 256, 0, stream>>>(
            pts, lights, d_all, w0, b0, w1, b1, w2, b2, w3, b3, nullptr, sdf);
    }
    finish_kernel<<<NRAY / 4, 256, 0, stream>>>(sdf, out);
}